// Round 4
// baseline (2744.009 us; speedup 1.0000x reference)
//
#include <hip/hip_runtime.h>
#include <hip/hip_fp16.h>
#include <math.h>

#define BB 128
#define TT 512
#define DD 256
#define HH 256
#define NG 1024  // 4*H

typedef _Float16 h2_t __attribute__((ext_vector_type(2)));
typedef _Float16 f16x8 __attribute__((ext_vector_type(8)));
typedef float f32x4 __attribute__((ext_vector_type(4)));

#if __has_builtin(__builtin_amdgcn_fdot2)
__device__ __forceinline__ float fdot2_(h2_t a, h2_t b, float c) {
    return __builtin_amdgcn_fdot2(a, b, c, false);
}
#else
__device__ __forceinline__ float fdot2_(h2_t a, h2_t b, float c) {
    return c + (float)a.x * (float)b.x + (float)a.y * (float)b.y;
}
#endif

__device__ __forceinline__ float sigmoidf_(float x) {
    return 1.0f / (1.0f + __expf(-x));
}
__device__ __forceinline__ float tanhf_(float x) {
    x = fminf(15.0f, fmaxf(-15.0f, x));
    float e = __expf(2.0f * x);
    return (e - 1.0f) / (e + 1.0f);
}

// Pack: packed col n = j*4+q <-> gate row g = q*256+j  (q: 0=i,1=f,2=g,3=o)
//  Wg16 [n][k] fp16           (MFMA GEMM B operand: B[k][n] = W[n][k], 16B/lane frags)
//  Wi16/Wh16 fp16 k-pair-major (rec/fused: halfs at ((k>>1)*1024 + n)*2 + (k&1))
//  bias_p[n] = b_ih[g] + b_hh[g]
__global__ void pack2(const float* __restrict__ W_ih, const float* __restrict__ W_hh,
                      const float* __restrict__ b_ih, const float* __restrict__ b_hh,
                      __half* __restrict__ Wg16, __half* __restrict__ Wi16,
                      __half* __restrict__ Wh16, float* __restrict__ bias_p) {
    int idx = blockIdx.x * 256 + threadIdx.x;   // 0..262143
    int n = idx >> 8;
    int k = idx & 255;
    int g = (n & 3) * 256 + (n >> 2);
    float wih = W_ih[g * 256 + k];
    float whh = W_hh[g * 256 + k];
    Wg16[n * 256 + k] = __float2half(wih);
    size_t hidx = ((size_t)(k >> 1) * 1024 + n) * 2 + (k & 1);
    Wi16[hidx] = __float2half(wih);
    Wh16[hidx] = __float2half(whh);
    if (idx < 1024) {
        int gg = (idx & 3) * 256 + (idx >> 2);
        bias_p[idx] = b_ih[gg] + b_hh[gg];
    }
}

// x fp32 -> fp16, 8 elements/thread
__global__ __launch_bounds__(256) void cvt_x(const float* __restrict__ X,
                                             __half* __restrict__ X16) {
    size_t i = ((size_t)blockIdx.x * 256 + threadIdx.x) * 8;
    float4 a = *(const float4*)&X[i];
    float4 b = *(const float4*)&X[i + 4];
    f16x8 v;
    v[0] = (_Float16)a.x; v[1] = (_Float16)a.y; v[2] = (_Float16)a.z; v[3] = (_Float16)a.w;
    v[4] = (_Float16)b.x; v[5] = (_Float16)b.y; v[6] = (_Float16)b.z; v[7] = (_Float16)b.w;
    *(f16x8*)&X16[i] = v;
}

// xg chunk GEMM via MFMA f16: M = 128*Tc (m = b*Tc + tt), N = 1024, K = 256.
// Block = 64x64 tile, 4 waves; wave w: rows w*16..+15, 4 col-groups of 16.
// A frag: lane holds A[m0 + (lane&15)][k = quad*8 + j]  (16B contiguous)
// B frag: lane holds B[k][n0 + (lane&15)] = Wg16[n][k..k+7] (16B contiguous)
// C/D: col = lane&15, row = quad*4 + reg  (verified layout)
__global__ __launch_bounds__(256) void xg_gemm_mfma(const __half* __restrict__ X16,
                                                    const __half* __restrict__ Wg16,
                                                    const float* __restrict__ bias_p,
                                                    __half* __restrict__ xg,
                                                    int t0, int lTc, int tcMask) {
    int tid = threadIdx.x;
    int w = tid >> 6, lane = tid & 63;
    int row16 = lane & 15, quad = lane >> 4;
    int m0 = blockIdx.x * 64 + w * 16;
    int n0 = blockIdx.y * 64;

    int mrow = m0 + row16;                                   // chunk-local row
    size_t xrow = (size_t)(mrow >> lTc) * 512 + t0 + (mrow & tcMask);
    const __half* aptr = X16 + xrow * 256 + quad * 8;
    f16x8 afrag[8];
#pragma unroll
    for (int kk = 0; kk < 8; ++kk)
        afrag[kk] = *(const f16x8*)(aptr + kk * 32);

#pragma unroll
    for (int cg = 0; cg < 4; ++cg) {
        int n = n0 + cg * 16 + row16;
        const __half* bptr = Wg16 + (size_t)n * 256 + quad * 8;
        f32x4 acc = {0.0f, 0.0f, 0.0f, 0.0f};
#pragma unroll
        for (int kk = 0; kk < 8; ++kk) {
            f16x8 bfrag = *(const f16x8*)(bptr + kk * 32);
            acc = __builtin_amdgcn_mfma_f32_16x16x32_f16(afrag[kk], bfrag, acc, 0, 0, 0);
        }
        float bias = bias_p[n];
#pragma unroll
        for (int r = 0; r < 4; ++r) {
            int mout = blockIdx.x * 64 + w * 16 + quad * 4 + r;  // chunk-local
            xg[(size_t)mout * 1024 + n] = __float2half(acc[r] + bias);
        }
    }
}

// Recurrence: 64 blocks x 1024 threads, 2 samples/block (weight L2 stream
// amortized over both). Thread (c = tid&255, kh = tid>>8): 4 gates of column c,
// k-quarter kh, both samples; fp16 weights, fp32 acc via v_dot2_f32_f16.
// Finalize: kh==0 handles sample A, kh==1 sample B (c/h state lives there).
__global__ __launch_bounds__(1024) void lstm_rec2(const __half* __restrict__ xg,
                                                  const __half* __restrict__ Wh16,
                                                  const int* __restrict__ x_len,
                                                  float* __restrict__ out,
                                                  __half* __restrict__ h_state,
                                                  float* __restrict__ c_state,
                                                  int t0, int Tc) {
    __shared__ __half hs[2][256];
    __shared__ float4 part[4][2][256];
    int tid = threadIdx.x;
    int c = tid & 255, kh = tid >> 8;     // kh wave-uniform
    int b0 = blockIdx.x * 2;
    float cst = 0.0f;
    int len = 0;
    if (kh < 2) {
        len = x_len[b0 + kh];
        if (t0 == 0) {
            hs[kh][c] = __float2half(0.0f);
        } else {
            hs[kh][c] = h_state[(b0 + kh) * 256 + c];
            cst = c_state[(b0 + kh) * 256 + c];
        }
    }
    __syncthreads();

    const uint4* wp = (const uint4*)(Wh16 + (size_t)(kh * 32) * 2048 + 8 * c);
    const __half* xgb = xg + (size_t)(b0 + kh) * Tc * 1024 + 4 * c;  // kh<2 only
    float* outb = out + ((size_t)(b0 + kh) * 512 + t0) * 256 + c;

    for (int tt = 0; tt < Tc; ++tt) {
        float4 accA = {0.0f, 0.0f, 0.0f, 0.0f};
        float4 accB = {0.0f, 0.0f, 0.0f, 0.0f};
#pragma unroll 8
        for (int i = 0; i < 32; ++i) {
            uint4 u = wp[(size_t)i * 256];          // 16B: 4 cols x 1 k-pair
            h2_t ha = ((const h2_t*)hs[0])[kh * 32 + i];   // LDS broadcast
            h2_t hb = ((const h2_t*)hs[1])[kh * 32 + i];
            accA.x = fdot2_(__builtin_bit_cast(h2_t, u.x), ha, accA.x);
            accA.y = fdot2_(__builtin_bit_cast(h2_t, u.y), ha, accA.y);
            accA.z = fdot2_(__builtin_bit_cast(h2_t, u.z), ha, accA.z);
            accA.w = fdot2_(__builtin_bit_cast(h2_t, u.w), ha, accA.w);
            accB.x = fdot2_(__builtin_bit_cast(h2_t, u.x), hb, accB.x);
            accB.y = fdot2_(__builtin_bit_cast(h2_t, u.y), hb, accB.y);
            accB.z = fdot2_(__builtin_bit_cast(h2_t, u.z), hb, accB.z);
            accB.w = fdot2_(__builtin_bit_cast(h2_t, u.w), hb, accB.w);
        }
        part[kh][0][c] = accA;
        part[kh][1][c] = accB;
        __syncthreads();
        if (kh < 2) {
            float4 p0 = part[0][kh][c], p1 = part[1][kh][c];
            float4 p2 = part[2][kh][c], p3 = part[3][kh][c];
            // xg fp16: 4 halfs for this column's 4 gates
            uint2 xr = *(const uint2*)(xgb + (size_t)tt * 1024);
            h2_t x01 = __builtin_bit_cast(h2_t, xr.x);
            h2_t x23 = __builtin_bit_cast(h2_t, xr.y);
            float gi = p0.x + p1.x + p2.x + p3.x + (float)x01.x;
            float gf = p0.y + p1.y + p2.y + p3.y + (float)x01.y;
            float gg = p0.z + p1.z + p2.z + p3.z + (float)x23.x;
            float go = p0.w + p1.w + p2.w + p3.w + (float)x23.y;
            float iv = sigmoidf_(gi), fv = sigmoidf_(gf);
            float gv = tanhf_(gg),   ov = sigmoidf_(go);
            cst = fv * cst + iv * gv;
            float h = ov * tanhf_(cst);
            int t = t0 + tt;
            outb[(size_t)tt * 256] = (t < len) ? h : 0.0f;
            hs[kh][c] = __float2half(h);
        }
        __syncthreads();
    }
    if (kh < 2) {
        h_state[(b0 + kh) * 256 + c] = hs[kh][c];
        c_state[(b0 + kh) * 256 + c] = cst;
    }
}

// Fallback (ws too small for any xg chunk): fused, streams both fp16 matrices.
__global__ __launch_bounds__(1024) void lstm_fused16(const float* __restrict__ X,
                                                     const __half* __restrict__ Wi16,
                                                     const __half* __restrict__ Wh16,
                                                     const float* __restrict__ bias_p,
                                                     const int* __restrict__ x_len,
                                                     float* __restrict__ out) {
    __shared__ __half hs_h[256];
    __shared__ __half xs_h[256];
    __shared__ float4 part[3][256];
    int tid = threadIdx.x;
    int c = tid & 255, kh = tid >> 8;
    int b = blockIdx.x;
    int len = x_len[b];
    float cst = 0.0f;
    float4 bias;
    if (kh == 0) {
        bias = *(const float4*)&bias_p[4 * c];
        hs_h[c] = __float2half(0.0f);
    }
    const uint4* wph = (const uint4*)(Wh16 + (size_t)(kh * 32) * 2048 + 8 * c);
    const uint4* wpi = (const uint4*)(Wi16 + (size_t)(kh * 32) * 2048 + 8 * c);
    float* outb = out + (size_t)b * 512 * 256 + c;
    __syncthreads();

    for (int t = 0; t < TT; ++t) {
        if (tid < 128) {
            float2 xv = *(const float2*)&X[((size_t)b * 512 + t) * 256 + 2 * tid];
            h2_t xh = {(_Float16)xv.x, (_Float16)xv.y};
            ((h2_t*)xs_h)[tid] = xh;
        }
        __syncthreads();
        float4 acc = {0.0f, 0.0f, 0.0f, 0.0f};
#pragma unroll 4
        for (int i = 0; i < 32; ++i) {
            uint4 uh = wph[(size_t)i * 256];
            uint4 ui = wpi[(size_t)i * 256];
            h2_t hv = ((const h2_t*)hs_h)[kh * 32 + i];
            h2_t xv = ((const h2_t*)xs_h)[kh * 32 + i];
            acc.x = fdot2_(__builtin_bit_cast(h2_t, uh.x), hv, acc.x);
            acc.y = fdot2_(__builtin_bit_cast(h2_t, uh.y), hv, acc.y);
            acc.z = fdot2_(__builtin_bit_cast(h2_t, uh.z), hv, acc.z);
            acc.w = fdot2_(__builtin_bit_cast(h2_t, uh.w), hv, acc.w);
            acc.x = fdot2_(__builtin_bit_cast(h2_t, ui.x), xv, acc.x);
            acc.y = fdot2_(__builtin_bit_cast(h2_t, ui.y), xv, acc.y);
            acc.z = fdot2_(__builtin_bit_cast(h2_t, ui.z), xv, acc.z);
            acc.w = fdot2_(__builtin_bit_cast(h2_t, ui.w), xv, acc.w);
        }
        if (kh) part[kh - 1][c] = acc;
        __syncthreads();
        if (kh == 0) {
            float4 p0 = part[0][c], p1 = part[1][c], p2 = part[2][c];
            float gi = acc.x + p0.x + p1.x + p2.x + bias.x;
            float gf = acc.y + p0.y + p1.y + p2.y + bias.y;
            float gg = acc.z + p0.z + p1.z + p2.z + bias.z;
            float go = acc.w + p0.w + p1.w + p2.w + bias.w;
            float iv = sigmoidf_(gi), fv = sigmoidf_(gf);
            float gv = tanhf_(gg),   ov = sigmoidf_(go);
            cst = fv * cst + iv * gv;
            float h = ov * tanhf_(cst);
            outb[(size_t)t * 256] = (t < len) ? h : 0.0f;
            hs_h[c] = __float2half(h);
        }
        __syncthreads();
    }
}

extern "C" void kernel_launch(void* const* d_in, const int* in_sizes, int n_in,
                              void* d_out, int out_size, void* d_ws, size_t ws_size,
                              hipStream_t stream) {
    const float* x     = (const float*)d_in[0];
    const int*   x_len = (const int*)d_in[1];
    const float* W_ih  = (const float*)d_in[2];
    const float* W_hh  = (const float*)d_in[3];
    const float* b_ih  = (const float*)d_in[4];
    const float* b_hh  = (const float*)d_in[5];
    float* out = (float*)d_out;

    char* ws = (char*)d_ws;
    __half* Wh16    = (__half*)(ws);                      // 512 KB
    __half* Wi16    = (__half*)(ws + 0x080000);           // 512 KB
    __half* Wg16    = (__half*)(ws + 0x100000);           // 512 KB
    float*  bias_p  = (float*)(ws + 0x180000);            // 4 KB
    __half* h_state = (__half*)(ws + 0x181000);           // 64 KB
    float*  c_state = (float*)(ws + 0x191000);            // 128 KB
    __half* x16     = (__half*)(ws + 0x1B1000);           // 32 MB
    size_t  o_xg    = 0x1B1000 + (size_t)0x2000000;
    __half* xg      = (__half*)(ws + o_xg);

    int Tc = 0;
    for (int cand = 512; cand >= 16; cand >>= 1)
        if (ws_size >= o_xg + (size_t)cand * 262144) { Tc = cand; break; }

    pack2<<<1024, 256, 0, stream>>>(W_ih, W_hh, b_ih, b_hh,
                                    Wg16, Wi16, Wh16, bias_p);
    if (Tc) {
        cvt_x<<<8192, 256, 0, stream>>>(x, x16);
        int lTc = 31 - __builtin_clz((unsigned)Tc);
        for (int t0 = 0; t0 < TT; t0 += Tc) {
            dim3 g(2 * Tc, 16);   // (128*Tc/64, 1024/64)
            xg_gemm_mfma<<<g, 256, 0, stream>>>(x16, Wg16, bias_p, xg,
                                                t0, lTc, Tc - 1);
            lstm_rec2<<<BB / 2, 1024, 0, stream>>>(xg, Wh16, x_len, out,
                                                   h_state, c_state, t0, Tc);
        }
    } else {
        lstm_fused16<<<BB, 1024, 0, stream>>>(x, Wi16, Wh16, bias_p, x_len, out);
    }
}

// Round 5
// 1885.982 us; speedup vs baseline: 1.4549x; 1.4549x over previous
//
#include <hip/hip_runtime.h>
#include <hip/hip_fp16.h>
#include <math.h>

#define BB 128
#define TT 512
#define DD 256
#define HH 256
#define NG 1024  // 4*H

typedef _Float16 h2_t __attribute__((ext_vector_type(2)));
typedef _Float16 f16x8 __attribute__((ext_vector_type(8)));
typedef float f32x4 __attribute__((ext_vector_type(4)));

#if __has_builtin(__builtin_amdgcn_fdot2)
__device__ __forceinline__ float fdot2_(h2_t a, h2_t b, float c) {
    return __builtin_amdgcn_fdot2(a, b, c, false);
}
#else
__device__ __forceinline__ float fdot2_(h2_t a, h2_t b, float c) {
    return c + (float)a.x * (float)b.x + (float)a.y * (float)b.y;
}
#endif

__device__ __forceinline__ float sigmoidf_(float x) {
    return 1.0f / (1.0f + __expf(-x));
}
__device__ __forceinline__ float tanhf_(float x) {
    x = fminf(15.0f, fmaxf(-15.0f, x));
    float e = __expf(2.0f * x);
    return (e - 1.0f) / (e + 1.0f);
}

// Pack: packed col n = j*4+q <-> gate row g = q*256+j  (q: 0=i,1=f,2=g,3=o)
//  Wg16 [n][k] fp16            (MFMA GEMM B operand)
//  Wi16/Wh16 fp16 k-pair-major (halfs at ((k>>1)*1024 + n)*2 + (k&1))
//  bias_p[n] = b_ih[g] + b_hh[g]
__global__ void pack2(const float* __restrict__ W_ih, const float* __restrict__ W_hh,
                      const float* __restrict__ b_ih, const float* __restrict__ b_hh,
                      __half* __restrict__ Wg16, __half* __restrict__ Wi16,
                      __half* __restrict__ Wh16, float* __restrict__ bias_p) {
    int idx = blockIdx.x * 256 + threadIdx.x;   // 0..262143
    int n = idx >> 8;
    int k = idx & 255;
    int g = (n & 3) * 256 + (n >> 2);
    float wih = W_ih[g * 256 + k];
    float whh = W_hh[g * 256 + k];
    Wg16[n * 256 + k] = __float2half(wih);
    size_t hidx = ((size_t)(k >> 1) * 1024 + n) * 2 + (k & 1);
    Wi16[hidx] = __float2half(wih);
    Wh16[hidx] = __float2half(whh);
    if (idx < 1024) {
        int gg = (idx & 3) * 256 + (idx >> 2);
        bias_p[idx] = b_ih[gg] + b_hh[gg];
    }
}

// x fp32 -> fp16, 8 elements/thread
__global__ __launch_bounds__(256) void cvt_x(const float* __restrict__ X,
                                             __half* __restrict__ X16) {
    size_t i = ((size_t)blockIdx.x * 256 + threadIdx.x) * 8;
    float4 a = *(const float4*)&X[i];
    float4 b = *(const float4*)&X[i + 4];
    f16x8 v;
    v[0] = (_Float16)a.x; v[1] = (_Float16)a.y; v[2] = (_Float16)a.z; v[3] = (_Float16)a.w;
    v[4] = (_Float16)b.x; v[5] = (_Float16)b.y; v[6] = (_Float16)b.z; v[7] = (_Float16)b.w;
    *(f16x8*)&X16[i] = v;
}

// xg chunk GEMM via MFMA f16: M = 128*Tc, N = 1024, K = 256.
// Block = 64x64 tile, 4 waves. Epilogue: per-wave LDS transpose (pad +8 to
// rotate banks) then uint4 coalesced fp16 stores (was 64 scalar 2-B stores).
__global__ __launch_bounds__(256) void xg_gemm_mfma(const __half* __restrict__ X16,
                                                    const __half* __restrict__ Wg16,
                                                    const float* __restrict__ bias_p,
                                                    __half* __restrict__ xg,
                                                    int t0, int lTc, int tcMask) {
    __shared__ __align__(16) __half st[4][16][72];
    int tid = threadIdx.x;
    int w = tid >> 6, lane = tid & 63;
    int row16 = lane & 15, quad = lane >> 4;
    int m0 = blockIdx.x * 64 + w * 16;
    int n0 = blockIdx.y * 64;

    int mrow = m0 + row16;                                   // chunk-local row
    size_t xrow = (size_t)(mrow >> lTc) * 512 + t0 + (mrow & tcMask);
    const __half* aptr = X16 + xrow * 256 + quad * 8;
    f16x8 afrag[8];
#pragma unroll
    for (int kk = 0; kk < 8; ++kk)
        afrag[kk] = *(const f16x8*)(aptr + kk * 32);

#pragma unroll
    for (int cg = 0; cg < 4; ++cg) {
        int n = n0 + cg * 16 + row16;
        const __half* bptr = Wg16 + (size_t)n * 256 + quad * 8;
        f32x4 acc = {0.0f, 0.0f, 0.0f, 0.0f};
#pragma unroll
        for (int kk = 0; kk < 8; ++kk) {
            f16x8 bfrag = *(const f16x8*)(bptr + kk * 32);
            acc = __builtin_amdgcn_mfma_f32_16x16x32_f16(afrag[kk], bfrag, acc, 0, 0, 0);
        }
        float bias = bias_p[n];
#pragma unroll
        for (int r = 0; r < 4; ++r)
            st[w][quad * 4 + r][cg * 16 + row16] = __float2half(acc[r] + bias);
    }
    __syncthreads();
    int ml = lane >> 2, cq = lane & 3;
    int mout = blockIdx.x * 64 + w * 16 + ml;                // chunk-local row
    const uint4* src = (const uint4*)&st[w][ml][cq * 16];
    uint4 v0 = src[0], v1 = src[1];
    *(uint4*)&xg[(size_t)mout * 1024 + n0 + cq * 16] = v0;
    *(uint4*)&xg[(size_t)mout * 1024 + n0 + cq * 16 + 8] = v1;
}

// Recurrence: 128 blocks (1 sample) x 1024 threads, 1 block/CU.
// Thread (c = tid&255, kh = tid>>8): 4 gates of column c, k-quarter kh
// (32 k-pairs). Weight residency per thread: k-pairs 0-19 in REGISTERS
// (loaded once, reused all Tc steps), 20-23 in LDS, 24-31 streamed from L2
// (128 KB/block/step -> 2 MB/XCD/step ~ 0.47 us port time).
// h broadcast from LDS as uint4 (4 h2 per read).
__global__ __launch_bounds__(1024) void lstm_rec3(const __half* __restrict__ xg,
                                                  const __half* __restrict__ Wh16,
                                                  const int* __restrict__ x_len,
                                                  float* __restrict__ out,
                                                  __half* __restrict__ h_state,
                                                  float* __restrict__ c_state,
                                                  int t0, int Tc) {
    __shared__ __half hs[256];
    __shared__ float4 part[4][256];       // 16 KB
    __shared__ uint4 lw[4096];            // [kh][i<4][c] : 64 KB
    int tid = threadIdx.x;
    int c = tid & 255, kh = tid >> 8;     // kh wave-uniform
    int b = blockIdx.x;
    int len = x_len[b];
    const uint4* W4 = (const uint4*)Wh16;     // index: p*256 + c  (p = k-pair)

    // LDS weight fill: group kh2, k-pairs kh2*32 + 20..23
    for (int j = tid; j < 4096; j += 1024) {
        int kh2 = j >> 10, i2 = (j >> 8) & 3, c2 = j & 255;
        lw[j] = W4[(size_t)(kh2 * 32 + 20 + i2) * 256 + c2];
    }
    // Register-resident weights: k-pairs kh*32 + 0..19
    const uint4* wp = W4 + (size_t)(kh * 32) * 256 + c;
    uint4 wreg[20];
#pragma unroll
    for (int i = 0; i < 20; ++i) wreg[i] = wp[(size_t)i * 256];

    float cst = 0.0f;
    if (kh == 0) {
        if (t0 == 0) {
            hs[c] = __float2half(0.0f);
        } else {
            hs[c] = h_state[b * 256 + c];
            cst = c_state[b * 256 + c];
        }
    }
    const __half* xgb = xg + (size_t)b * Tc * 1024 + 4 * c;
    float* outb = out + ((size_t)b * 512 + t0) * 256 + c;
    __syncthreads();

    const uint4* hs4 = (const uint4*)hs;      // uint4 m covers h2 indices 4m..4m+3

    for (int tt = 0; tt < Tc; ++tt) {
        uint2 xr;
        if (kh == 0) xr = *(const uint2*)(xgb + (size_t)tt * 1024);
        float4 acc = {0.0f, 0.0f, 0.0f, 0.0f};
#pragma unroll
        for (int j = 0; j < 8; ++j) {
            uint4 hv = hs4[kh * 8 + j];       // 4 h2: k-pairs kh*32 + 4j .. +3
            h2_t h0 = __builtin_bit_cast(h2_t, hv.x);
            h2_t h1 = __builtin_bit_cast(h2_t, hv.y);
            h2_t h2 = __builtin_bit_cast(h2_t, hv.z);
            h2_t h3 = __builtin_bit_cast(h2_t, hv.w);
            h2_t hq[4] = {h0, h1, h2, h3};
#pragma unroll
            for (int q = 0; q < 4; ++q) {
                int i = j * 4 + q;
                uint4 u;
                if (i < 20)      u = wreg[i];
                else if (i < 24) u = lw[(kh * 4 + (i - 20)) * 256 + c];
                else             u = wp[(size_t)i * 256];
                acc.x = fdot2_(__builtin_bit_cast(h2_t, u.x), hq[q], acc.x);
                acc.y = fdot2_(__builtin_bit_cast(h2_t, u.y), hq[q], acc.y);
                acc.z = fdot2_(__builtin_bit_cast(h2_t, u.z), hq[q], acc.z);
                acc.w = fdot2_(__builtin_bit_cast(h2_t, u.w), hq[q], acc.w);
            }
        }
        part[kh][c] = acc;
        __syncthreads();
        if (kh == 0) {
            float4 p0 = part[0][c], p1 = part[1][c], p2 = part[2][c], p3 = part[3][c];
            h2_t x01 = __builtin_bit_cast(h2_t, xr.x);
            h2_t x23 = __builtin_bit_cast(h2_t, xr.y);
            float gi = p0.x + p1.x + p2.x + p3.x + (float)x01.x;
            float gf = p0.y + p1.y + p2.y + p3.y + (float)x01.y;
            float gg = p0.z + p1.z + p2.z + p3.z + (float)x23.x;
            float go = p0.w + p1.w + p2.w + p3.w + (float)x23.y;
            float iv = sigmoidf_(gi), fv = sigmoidf_(gf);
            float gv = tanhf_(gg),   ov = sigmoidf_(go);
            cst = fv * cst + iv * gv;
            float h = ov * tanhf_(cst);
            outb[(size_t)tt * 256] = (t0 + tt < len) ? h : 0.0f;
            hs[c] = __float2half(h);
        }
        __syncthreads();
    }
    if (kh == 0) {
        h_state[b * 256 + c] = hs[c];
        c_state[b * 256 + c] = cst;
    }
}

// Fallback (ws too small for any xg chunk): fused, streams both fp16 matrices.
__global__ __launch_bounds__(1024) void lstm_fused16(const float* __restrict__ X,
                                                     const __half* __restrict__ Wi16,
                                                     const __half* __restrict__ Wh16,
                                                     const float* __restrict__ bias_p,
                                                     const int* __restrict__ x_len,
                                                     float* __restrict__ out) {
    __shared__ __half hs_h[256];
    __shared__ __half xs_h[256];
    __shared__ float4 part[3][256];
    int tid = threadIdx.x;
    int c = tid & 255, kh = tid >> 8;
    int b = blockIdx.x;
    int len = x_len[b];
    float cst = 0.0f;
    float4 bias;
    if (kh == 0) {
        bias = *(const float4*)&bias_p[4 * c];
        hs_h[c] = __float2half(0.0f);
    }
    const uint4* wph = (const uint4*)(Wh16 + (size_t)(kh * 32) * 2048 + 8 * c);
    const uint4* wpi = (const uint4*)(Wi16 + (size_t)(kh * 32) * 2048 + 8 * c);
    float* outb = out + (size_t)b * 512 * 256 + c;
    __syncthreads();

    for (int t = 0; t < TT; ++t) {
        if (tid < 128) {
            float2 xv = *(const float2*)&X[((size_t)b * 512 + t) * 256 + 2 * tid];
            h2_t xh = {(_Float16)xv.x, (_Float16)xv.y};
            ((h2_t*)xs_h)[tid] = xh;
        }
        __syncthreads();
        float4 acc = {0.0f, 0.0f, 0.0f, 0.0f};
#pragma unroll 4
        for (int i = 0; i < 32; ++i) {
            uint4 uh = wph[(size_t)i * 256];
            uint4 ui = wpi[(size_t)i * 256];
            h2_t hv = ((const h2_t*)hs_h)[kh * 32 + i];
            h2_t xv = ((const h2_t*)xs_h)[kh * 32 + i];
            acc.x = fdot2_(__builtin_bit_cast(h2_t, uh.x), hv, acc.x);
            acc.y = fdot2_(__builtin_bit_cast(h2_t, uh.y), hv, acc.y);
            acc.z = fdot2_(__builtin_bit_cast(h2_t, uh.z), hv, acc.z);
            acc.w = fdot2_(__builtin_bit_cast(h2_t, uh.w), hv, acc.w);
            acc.x = fdot2_(__builtin_bit_cast(h2_t, ui.x), xv, acc.x);
            acc.y = fdot2_(__builtin_bit_cast(h2_t, ui.y), xv, acc.y);
            acc.z = fdot2_(__builtin_bit_cast(h2_t, ui.z), xv, acc.z);
            acc.w = fdot2_(__builtin_bit_cast(h2_t, ui.w), xv, acc.w);
        }
        if (kh) part[kh - 1][c] = acc;
        __syncthreads();
        if (kh == 0) {
            float4 p0 = part[0][c], p1 = part[1][c], p2 = part[2][c];
            float gi = acc.x + p0.x + p1.x + p2.x + bias.x;
            float gf = acc.y + p0.y + p1.y + p2.y + bias.y;
            float gg = acc.z + p0.z + p1.z + p2.z + bias.z;
            float go = acc.w + p0.w + p1.w + p2.w + bias.w;
            float iv = sigmoidf_(gi), fv = sigmoidf_(gf);
            float gv = tanhf_(gg),   ov = sigmoidf_(go);
            cst = fv * cst + iv * gv;
            float h = ov * tanhf_(cst);
            outb[(size_t)t * 256] = (t < len) ? h : 0.0f;
            hs_h[c] = __float2half(h);
        }
        __syncthreads();
    }
}

extern "C" void kernel_launch(void* const* d_in, const int* in_sizes, int n_in,
                              void* d_out, int out_size, void* d_ws, size_t ws_size,
                              hipStream_t stream) {
    const float* x     = (const float*)d_in[0];
    const int*   x_len = (const int*)d_in[1];
    const float* W_ih  = (const float*)d_in[2];
    const float* W_hh  = (const float*)d_in[3];
    const float* b_ih  = (const float*)d_in[4];
    const float* b_hh  = (const float*)d_in[5];
    float* out = (float*)d_out;

    char* ws = (char*)d_ws;
    __half* Wh16    = (__half*)(ws);                      // 512 KB
    __half* Wi16    = (__half*)(ws + 0x080000);           // 512 KB
    __half* Wg16    = (__half*)(ws + 0x100000);           // 512 KB
    float*  bias_p  = (float*)(ws + 0x180000);            // 4 KB
    __half* h_state = (__half*)(ws + 0x181000);           // 64 KB
    float*  c_state = (float*)(ws + 0x191000);            // 128 KB
    __half* x16     = (__half*)(ws + 0x1B1000);           // 33.6 MB
    size_t  o_xg    = 0x1B1000 + (size_t)0x2004000;
    __half* xg      = (__half*)(ws + o_xg);

    int Tc = 0;
    for (int cand = 512; cand >= 16; cand >>= 1)
        if (ws_size >= o_xg + (size_t)cand * 262144) { Tc = cand; break; }

    pack2<<<1024, 256, 0, stream>>>(W_ih, W_hh, b_ih, b_hh,
                                    Wg16, Wi16, Wh16, bias_p);
    if (Tc) {
        cvt_x<<<8192, 256, 0, stream>>>(x, x16);
        int lTc = 31 - __builtin_clz((unsigned)Tc);
        for (int t0 = 0; t0 < TT; t0 += Tc) {
            dim3 g(2 * Tc, 16);   // (128*Tc/64, 1024/64)
            xg_gemm_mfma<<<g, 256, 0, stream>>>(x16, Wg16, bias_p, xg,
                                                t0, lTc, Tc - 1);
            lstm_rec3<<<BB, 1024, 0, stream>>>(xg, Wh16, x_len, out,
                                               h_state, c_state, t0, Tc);
        }
    } else {
        lstm_fused16<<<BB, 1024, 0, stream>>>(x, Wi16, Wh16, bias_p, x_len, out);
    }
}

// Round 6
// 1383.021 us; speedup vs baseline: 1.9841x; 1.3637x over previous
//
#include <hip/hip_runtime.h>
#include <hip/hip_fp16.h>
#include <math.h>

#define BB 128
#define TT 512
#define DD 256
#define HH 256
#define NG 1024  // 4*H

typedef _Float16 h2_t __attribute__((ext_vector_type(2)));
typedef _Float16 f16x8 __attribute__((ext_vector_type(8)));
typedef float f32x4 __attribute__((ext_vector_type(4)));

#if __has_builtin(__builtin_amdgcn_fdot2)
__device__ __forceinline__ float fdot2_(h2_t a, h2_t b, float c) {
    return __builtin_amdgcn_fdot2(a, b, c, false);
}
#else
__device__ __forceinline__ float fdot2_(h2_t a, h2_t b, float c) {
    return c + (float)a.x * (float)b.x + (float)a.y * (float)b.y;
}
#endif

__device__ __forceinline__ float sigmoidf_(float x) {
    return 1.0f / (1.0f + __expf(-x));
}
__device__ __forceinline__ float tanhf_(float x) {
    x = fminf(15.0f, fmaxf(-15.0f, x));
    float e = __expf(2.0f * x);
    return (e - 1.0f) / (e + 1.0f);
}
__device__ __forceinline__ void dot4_(float4& acc, uint4 u, h2_t h) {
    acc.x = fdot2_(__builtin_bit_cast(h2_t, u.x), h, acc.x);
    acc.y = fdot2_(__builtin_bit_cast(h2_t, u.y), h, acc.y);
    acc.z = fdot2_(__builtin_bit_cast(h2_t, u.z), h, acc.z);
    acc.w = fdot2_(__builtin_bit_cast(h2_t, u.w), h, acc.w);
}

// Pack: packed col n = j*4+q <-> gate row g = q*256+j  (q: 0=i,1=f,2=g,3=o)
//  Wg16 [n][k] fp16            (MFMA GEMM B operand)
//  Wi16/Wh16 fp16 k-pair-major (halfs at ((k>>1)*1024 + n)*2 + (k&1))
//  bias_p[n] = b_ih[g] + b_hh[g]
__global__ void pack2(const float* __restrict__ W_ih, const float* __restrict__ W_hh,
                      const float* __restrict__ b_ih, const float* __restrict__ b_hh,
                      __half* __restrict__ Wg16, __half* __restrict__ Wi16,
                      __half* __restrict__ Wh16, float* __restrict__ bias_p) {
    int idx = blockIdx.x * 256 + threadIdx.x;   // 0..262143
    int n = idx >> 8;
    int k = idx & 255;
    int g = (n & 3) * 256 + (n >> 2);
    float wih = W_ih[g * 256 + k];
    float whh = W_hh[g * 256 + k];
    Wg16[n * 256 + k] = __float2half(wih);
    size_t hidx = ((size_t)(k >> 1) * 1024 + n) * 2 + (k & 1);
    Wi16[hidx] = __float2half(wih);
    Wh16[hidx] = __float2half(whh);
    if (idx < 1024) {
        int gg = (idx & 3) * 256 + (idx >> 2);
        bias_p[idx] = b_ih[gg] + b_hh[gg];
    }
}

// x fp32 -> fp16, 8 elements/thread
__global__ __launch_bounds__(256) void cvt_x(const float* __restrict__ X,
                                             __half* __restrict__ X16) {
    size_t i = ((size_t)blockIdx.x * 256 + threadIdx.x) * 8;
    float4 a = *(const float4*)&X[i];
    float4 b = *(const float4*)&X[i + 4];
    f16x8 v;
    v[0] = (_Float16)a.x; v[1] = (_Float16)a.y; v[2] = (_Float16)a.z; v[3] = (_Float16)a.w;
    v[4] = (_Float16)b.x; v[5] = (_Float16)b.y; v[6] = (_Float16)b.z; v[7] = (_Float16)b.w;
    *(f16x8*)&X16[i] = v;
}

// xg chunk GEMM via MFMA f16: M = 128*Tc, N = 1024, K = 256.
// Block = 64x64 tile, 4 waves. Epilogue: per-wave LDS transpose then uint4
// coalesced fp16 stores.
__global__ __launch_bounds__(256) void xg_gemm_mfma(const __half* __restrict__ X16,
                                                    const __half* __restrict__ Wg16,
                                                    const float* __restrict__ bias_p,
                                                    __half* __restrict__ xg,
                                                    int t0, int lTc, int tcMask) {
    __shared__ __align__(16) __half st[4][16][72];
    int tid = threadIdx.x;
    int w = tid >> 6, lane = tid & 63;
    int row16 = lane & 15, quad = lane >> 4;
    int m0 = blockIdx.x * 64 + w * 16;
    int n0 = blockIdx.y * 64;

    int mrow = m0 + row16;                                   // chunk-local row
    size_t xrow = (size_t)(mrow >> lTc) * 512 + t0 + (mrow & tcMask);
    const __half* aptr = X16 + xrow * 256 + quad * 8;
    f16x8 afrag[8];
#pragma unroll
    for (int kk = 0; kk < 8; ++kk)
        afrag[kk] = *(const f16x8*)(aptr + kk * 32);

#pragma unroll
    for (int cg = 0; cg < 4; ++cg) {
        int n = n0 + cg * 16 + row16;
        const __half* bptr = Wg16 + (size_t)n * 256 + quad * 8;
        f32x4 acc = {0.0f, 0.0f, 0.0f, 0.0f};
#pragma unroll
        for (int kk = 0; kk < 8; ++kk) {
            f16x8 bfrag = *(const f16x8*)(bptr + kk * 32);
            acc = __builtin_amdgcn_mfma_f32_16x16x32_f16(afrag[kk], bfrag, acc, 0, 0, 0);
        }
        float bias = bias_p[n];
#pragma unroll
        for (int r = 0; r < 4; ++r)
            st[w][quad * 4 + r][cg * 16 + row16] = __float2half(acc[r] + bias);
    }
    __syncthreads();
    int ml = lane >> 2, cq = lane & 3;
    int mout = blockIdx.x * 64 + w * 16 + ml;                // chunk-local row
    const uint4* src = (const uint4*)&st[w][ml][cq * 16];
    uint4 v0 = src[0], v1 = src[1];
    *(uint4*)&xg[(size_t)mout * 1024 + n0 + cq * 16] = v0;
    *(uint4*)&xg[(size_t)mout * 1024 + n0 + cq * 16 + 8] = v1;
}

// Recurrence: 128 blocks (1 sample) x 1024 threads, 1 block/CU.
// __launch_bounds__(1024, 4): 4 waves/SIMD -> 128-VGPR budget (R5's missing
// 2nd arg made the compiler cap at 64 VGPR and spill wreg to scratch).
// Thread (c = tid&255, kh = tid>>8): 4 gates of column c, k-quarter kh
// (32 k-pairs). Residency: k-pairs 0-19 in REGISTERS (80 VGPR, loaded once),
// 20-27 in LDS (128 KB), 28-31 streamed from L2 (64 KB/block/step, issued
// first so they fly during the 112 resident dot2s).
__global__ __launch_bounds__(1024, 4) void lstm_rec4(const __half* __restrict__ xg,
                                                     const __half* __restrict__ Wh16,
                                                     const int* __restrict__ x_len,
                                                     float* __restrict__ out,
                                                     __half* __restrict__ h_state,
                                                     float* __restrict__ c_state,
                                                     int t0, int Tc) {
    __shared__ __half hs[256];
    __shared__ float4 part[4][256];       // 16 KB
    __shared__ uint4 lw[8192];            // [kh][i<8][c] : 128 KB
    int tid = threadIdx.x;
    int c = tid & 255, kh = tid >> 8;     // kh wave-uniform
    int b = blockIdx.x;
    int len = x_len[b];
    const uint4* W4 = (const uint4*)Wh16;     // index: p*256 + c  (p = k-pair)

    // LDS weight fill: group kh2, k-pairs kh2*32 + 20..27
    for (int j = tid; j < 8192; j += 1024) {
        int kh2 = j >> 11, i2 = (j >> 8) & 7, c2 = j & 255;
        lw[j] = W4[(size_t)(kh2 * 32 + 20 + i2) * 256 + c2];
    }
    // Register-resident weights: k-pairs kh*32 + 0..19
    const uint4* wp = W4 + (size_t)(kh * 32) * 256 + c;
    uint4 wreg[20];
#pragma unroll
    for (int i = 0; i < 20; ++i) wreg[i] = wp[(size_t)i * 256];

    float cst = 0.0f;
    if (kh == 0) {
        if (t0 == 0) {
            hs[c] = __float2half(0.0f);
        } else {
            hs[c] = h_state[b * 256 + c];
            cst = c_state[b * 256 + c];
        }
    }
    const __half* xgb = xg + (size_t)b * Tc * 1024 + 4 * c;
    float* outb = out + ((size_t)b * 512 + t0) * 256 + c;
    __syncthreads();

    const uint4* hs4 = (const uint4*)hs;      // uint4 m covers h2 indices 4m..4m+3
    const uint4* lwb = lw + kh * 2048 + c;    // [i2*256] strides

    for (int tt = 0; tt < Tc; ++tt) {
        // streamed weights first (in flight during resident dot2s)
        uint4 s0 = wp[(size_t)28 * 256];
        uint4 s1 = wp[(size_t)29 * 256];
        uint4 s2 = wp[(size_t)30 * 256];
        uint4 s3 = wp[(size_t)31 * 256];
        uint2 xr;
        if (kh == 0) xr = *(const uint2*)(xgb + (size_t)tt * 1024);

        float4 acc = {0.0f, 0.0f, 0.0f, 0.0f};
        // j = 0..4: k-pairs 4j..4j+3 all in registers
#pragma unroll
        for (int j = 0; j < 5; ++j) {
            uint4 hv = hs4[kh * 8 + j];
            dot4_(acc, wreg[j * 4 + 0], __builtin_bit_cast(h2_t, hv.x));
            dot4_(acc, wreg[j * 4 + 1], __builtin_bit_cast(h2_t, hv.y));
            dot4_(acc, wreg[j * 4 + 2], __builtin_bit_cast(h2_t, hv.z));
            dot4_(acc, wreg[j * 4 + 3], __builtin_bit_cast(h2_t, hv.w));
        }
        // j = 5,6: k-pairs 20..27 from LDS
#pragma unroll
        for (int j = 5; j < 7; ++j) {
            uint4 hv = hs4[kh * 8 + j];
            int i0 = (j - 5) * 4;
            dot4_(acc, lwb[(i0 + 0) * 256], __builtin_bit_cast(h2_t, hv.x));
            dot4_(acc, lwb[(i0 + 1) * 256], __builtin_bit_cast(h2_t, hv.y));
            dot4_(acc, lwb[(i0 + 2) * 256], __builtin_bit_cast(h2_t, hv.z));
            dot4_(acc, lwb[(i0 + 3) * 256], __builtin_bit_cast(h2_t, hv.w));
        }
        // j = 7: k-pairs 28..31 streamed
        {
            uint4 hv = hs4[kh * 8 + 7];
            dot4_(acc, s0, __builtin_bit_cast(h2_t, hv.x));
            dot4_(acc, s1, __builtin_bit_cast(h2_t, hv.y));
            dot4_(acc, s2, __builtin_bit_cast(h2_t, hv.z));
            dot4_(acc, s3, __builtin_bit_cast(h2_t, hv.w));
        }
        part[kh][c] = acc;
        __syncthreads();
        if (kh == 0) {
            float4 p0 = part[0][c], p1 = part[1][c], p2 = part[2][c], p3 = part[3][c];
            h2_t x01 = __builtin_bit_cast(h2_t, xr.x);
            h2_t x23 = __builtin_bit_cast(h2_t, xr.y);
            float gi = p0.x + p1.x + p2.x + p3.x + (float)x01.x;
            float gf = p0.y + p1.y + p2.y + p3.y + (float)x01.y;
            float gg = p0.z + p1.z + p2.z + p3.z + (float)x23.x;
            float go = p0.w + p1.w + p2.w + p3.w + (float)x23.y;
            float iv = sigmoidf_(gi), fv = sigmoidf_(gf);
            float gv = tanhf_(gg),   ov = sigmoidf_(go);
            cst = fv * cst + iv * gv;
            float h = ov * tanhf_(cst);
            outb[(size_t)tt * 256] = (t0 + tt < len) ? h : 0.0f;
            hs[c] = __float2half(h);
        }
        __syncthreads();
    }
    if (kh == 0) {
        h_state[b * 256 + c] = hs[c];
        c_state[b * 256 + c] = cst;
    }
}

// Fallback (ws too small for any xg chunk): fused, streams both fp16 matrices.
__global__ __launch_bounds__(1024) void lstm_fused16(const float* __restrict__ X,
                                                     const __half* __restrict__ Wi16,
                                                     const __half* __restrict__ Wh16,
                                                     const float* __restrict__ bias_p,
                                                     const int* __restrict__ x_len,
                                                     float* __restrict__ out) {
    __shared__ __half hs_h[256];
    __shared__ __half xs_h[256];
    __shared__ float4 part[3][256];
    int tid = threadIdx.x;
    int c = tid & 255, kh = tid >> 8;
    int b = blockIdx.x;
    int len = x_len[b];
    float cst = 0.0f;
    float4 bias;
    if (kh == 0) {
        bias = *(const float4*)&bias_p[4 * c];
        hs_h[c] = __float2half(0.0f);
    }
    const uint4* wph = (const uint4*)(Wh16 + (size_t)(kh * 32) * 2048 + 8 * c);
    const uint4* wpi = (const uint4*)(Wi16 + (size_t)(kh * 32) * 2048 + 8 * c);
    float* outb = out + (size_t)b * 512 * 256 + c;
    __syncthreads();

    for (int t = 0; t < TT; ++t) {
        if (tid < 128) {
            float2 xv = *(const float2*)&X[((size_t)b * 512 + t) * 256 + 2 * tid];
            h2_t xh = {(_Float16)xv.x, (_Float16)xv.y};
            ((h2_t*)xs_h)[tid] = xh;
        }
        __syncthreads();
        float4 acc = {0.0f, 0.0f, 0.0f, 0.0f};
#pragma unroll 4
        for (int i = 0; i < 32; ++i) {
            uint4 uh = wph[(size_t)i * 256];
            uint4 ui = wpi[(size_t)i * 256];
            h2_t hv = ((const h2_t*)hs_h)[kh * 32 + i];
            h2_t xv = ((const h2_t*)xs_h)[kh * 32 + i];
            dot4_(acc, uh, hv);
            dot4_(acc, ui, xv);
        }
        if (kh) part[kh - 1][c] = acc;
        __syncthreads();
        if (kh == 0) {
            float4 p0 = part[0][c], p1 = part[1][c], p2 = part[2][c];
            float gi = acc.x + p0.x + p1.x + p2.x + bias.x;
            float gf = acc.y + p0.y + p1.y + p2.y + bias.y;
            float gg = acc.z + p0.z + p1.z + p2.z + bias.z;
            float go = acc.w + p0.w + p1.w + p2.w + bias.w;
            float iv = sigmoidf_(gi), fv = sigmoidf_(gf);
            float gv = tanhf_(gg),   ov = sigmoidf_(go);
            cst = fv * cst + iv * gv;
            float h = ov * tanhf_(cst);
            outb[(size_t)t * 256] = (t < len) ? h : 0.0f;
            hs_h[c] = __float2half(h);
        }
        __syncthreads();
    }
}

extern "C" void kernel_launch(void* const* d_in, const int* in_sizes, int n_in,
                              void* d_out, int out_size, void* d_ws, size_t ws_size,
                              hipStream_t stream) {
    const float* x     = (const float*)d_in[0];
    const int*   x_len = (const int*)d_in[1];
    const float* W_ih  = (const float*)d_in[2];
    const float* W_hh  = (const float*)d_in[3];
    const float* b_ih  = (const float*)d_in[4];
    const float* b_hh  = (const float*)d_in[5];
    float* out = (float*)d_out;

    char* ws = (char*)d_ws;
    __half* Wh16    = (__half*)(ws);                      // 512 KB
    __half* Wi16    = (__half*)(ws + 0x080000);           // 512 KB
    __half* Wg16    = (__half*)(ws + 0x100000);           // 512 KB
    float*  bias_p  = (float*)(ws + 0x180000);            // 4 KB
    __half* h_state = (__half*)(ws + 0x181000);           // 64 KB
    float*  c_state = (float*)(ws + 0x191000);            // 128 KB
    __half* x16     = (__half*)(ws + 0x1B1000);           // 33.6 MB
    size_t  o_xg    = 0x1B1000 + (size_t)0x2004000;
    __half* xg      = (__half*)(ws + o_xg);

    int Tc = 0;
    for (int cand = 512; cand >= 16; cand >>= 1)
        if (ws_size >= o_xg + (size_t)cand * 262144) { Tc = cand; break; }

    pack2<<<1024, 256, 0, stream>>>(W_ih, W_hh, b_ih, b_hh,
                                    Wg16, Wi16, Wh16, bias_p);
    if (Tc) {
        cvt_x<<<8192, 256, 0, stream>>>(x, x16);
        int lTc = 31 - __builtin_clz((unsigned)Tc);
        for (int t0 = 0; t0 < TT; t0 += Tc) {
            dim3 g(2 * Tc, 16);   // (128*Tc/64, 1024/64)
            xg_gemm_mfma<<<g, 256, 0, stream>>>(x16, Wg16, bias_p, xg,
                                                t0, lTc, Tc - 1);
            lstm_rec4<<<BB, 1024, 0, stream>>>(xg, Wh16, x_len, out,
                                               h_state, c_state, t0, Tc);
        }
    } else {
        lstm_fused16<<<BB, 1024, 0, stream>>>(x, Wi16, Wh16, bias_p, x_len, out);
    }
}